// Round 11
// baseline (168.777 us; speedup 1.0000x reference)
//
#include <hip/hip_runtime.h>

// Problem constants (from reference)
#define BATCH   16
#define NTGT    50
#define NCLS    80
#define GRIDN   80                  // H = W
#define NANCH   3
#define PLANE   (GRIDN*GRIDN)       // 6400
#define CHPA    (5+NCLS)            // 85
#define CHTOT   (NANCH*CHPA)        // 255

#define OBJ_BLOCKS   (BATCH*NTGT)   // 800 — one block per (batch, target)
#define NOOBJ_BLOCKS 96             // grid-stride float4 over 48 conf planes
#define TOTAL_BLOCKS (OBJ_BLOCKS + NOOBJ_BLOCKS)  // 896
#define BLOCKSZ      128

// scaled anchors = ANCHORS / (640/80) = ANCHORS / 8
__device__ __constant__ float c_aw[3] = {14.5f, 19.5f, 46.625f};
__device__ __constant__ float c_ah[3] = {11.25f, 24.75f, 40.75f};

__device__ __forceinline__ float softplusf(float x) {
    return fmaxf(x, 0.0f) + log1pf(expf(-fabsf(x)));
}
__device__ __forceinline__ float sigmoidf_(float x) {
    return 1.0f / (1.0f + expf(-x));
}

// ---------------------------------------------------------------------------
// Single fused kernel (one graph node after a 4-byte memset):
//   blocks [0, 800):   obj path — block (b,t) recomputes per-batch target keys
//                      (targets: 16 KB, L2-hot), dedups; if target t owns its
//                      cell, 85 lanes gather the cell's channels in ONE
//                      parallel round.
//   blocks [800, 896): noobj path — dense softplus(sigmoid(conf)) sum,
//                      contiguous float4 loads (1.2 MB).
// Completion: every block writes partial[blk], device-fence, atomic ticket;
// the LAST block to finish re-fences, sums the 896 partials, writes out[0].
// Counter is zeroed each launch by the tiny memset node (poison-safe).
// ---------------------------------------------------------------------------
__global__ __launch_bounds__(BLOCKSZ) void kmain(const float* __restrict__ pred,
                      const float* __restrict__ targets,
                      double* __restrict__ partial,
                      unsigned int* __restrict__ cnt,
                      float* __restrict__ out) {
    const int blk = blockIdx.x;
    const int tid = threadIdx.x;

    const double w_coord = 5.0 / (double)BATCH;
    const double w_one   = 1.0 / (double)BATCH;
    const double w_noobj = 0.5 / (double)BATCH;

    __shared__ int    s_key[NTGT];
    __shared__ int    s_valid[NTGT];
    __shared__ int    s_cls[NTGT];
    __shared__ float  s_g[4];          // gx,gy,gw,gh of THIS block's target
    __shared__ double s_red[2];
    __shared__ int    s_last;

    double local = 0.0;

    if (blk < OBJ_BLOCKS) {
        const int b = blk / NTGT;
        const int t = blk % NTGT;

        if (tid < NTGT) {
            const float* t5 = targets + ((size_t)b * NTGT + tid) * 5;
            float c = t5[0], x = t5[1], y = t5[2], w = t5[3], h = t5[4];
            float ssum = c + x + y + w + h;
            float gx = x * (float)GRIDN, gy = y * (float)GRIDN;
            float gw = w * (float)GRIDN, gh = h * (float)GRIDN;
            int gi = (int)gx, gj = (int)gy;          // trunc == floor (positive)
            int valid = (ssum != 0.0f) && (gi < GRIDN) && (gj < GRIDN);
            float best = -1.0f; int bestn = 0;
            #pragma unroll
            for (int a = 0; a < NANCH; a++) {
                float inter = fminf(gw, c_aw[a]) * fminf(gh, c_ah[a]);
                float iou   = inter / (gw * gh + c_aw[a] * c_ah[a] - inter + 1e-6f);
                if (iou > best) { best = iou; bestn = a; }   // first-max wins == argmax
            }
            s_key[tid]   = bestn * PLANE + gj * GRIDN + gi;
            s_valid[tid] = valid;
            s_cls[tid]   = (int)c;
            if (tid == t) { s_g[0] = gx; s_g[1] = gy; s_g[2] = gw; s_g[3] = gh; }
        }
        __syncthreads();

        // last-write-wins ownership (uniform across block)
        const int mykey = s_key[t];
        bool win = (s_valid[t] != 0);
        if (win) {
            for (int t2 = t + 1; t2 < NTGT; t2++)
                if (s_valid[t2] && s_key[t2] == mykey) { win = false; break; }
        }

        if (win) {
            // tcls = UNION of class ids of all colliding valid targets
            unsigned long long mlo = 0ull; unsigned int mhi = 0u;
            for (int t2 = 0; t2 < NTGT; t2++) {
                if (s_valid[t2] && s_key[t2] == mykey) {
                    int c = s_cls[t2];
                    if (c < 64) mlo |= 1ull << c; else mhi |= 1u << (c - 64);
                }
            }

            const int a   = mykey / PLANE;
            const int rem = mykey % PLANE;               // gj*80 + gi
            const size_t base = ((size_t)b * CHTOT + (size_t)a * CHPA) * PLANE + rem;

            if (tid < NCLS) {
                // BCE(z,t) = softplus(z) - t*z
                float z = pred[base + (size_t)(5 + tid) * PLANE];
                bool inset = (tid < 64) ? ((mlo >> tid) & 1ull)
                                        : ((mhi >> (tid - 64)) & 1u);
                local = w_one * ((double)softplusf(z) - (inset ? (double)z : 0.0));
            } else if (tid == NCLS) {                    // x (BCE on sigmoid output)
                float sx = sigmoidf_(pred[base]);
                float tx = s_g[0] - (float)(rem % GRIDN);
                local = w_coord * ((double)softplusf(sx) - (double)tx * (double)sx);
            } else if (tid == NCLS + 1) {                // y
                float sy = sigmoidf_(pred[base + (size_t)PLANE]);
                float ty = s_g[1] - (float)(rem / GRIDN);
                local = w_coord * ((double)softplusf(sy) - (double)ty * (double)sy);
            } else if (tid == NCLS + 2) {                // w (squared error, raw)
                float pw = pred[base + 2 * (size_t)PLANE];
                float tw = logf(s_g[2] / c_aw[a] + 1e-16f);
                float d = pw - tw;
                local = w_coord * (double)d * (double)d;
            } else if (tid == NCLS + 3) {                // h
                float ph = pred[base + 3 * (size_t)PLANE];
                float th = logf(s_g[3] / c_ah[a] + 1e-16f);
                float d = ph - th;
                local = w_coord * (double)d * (double)d;
            } else if (tid == NCLS + 4) {                // conf at obj cell
                float conf = sigmoidf_(pred[base + 4 * (size_t)PLANE]);
                float sp = softplusf(conf);
                // BCE(conf,1)=softplus(conf)-conf ; remove cell from dense noobj sum
                local = w_one * ((double)sp - (double)conf) - w_noobj * (double)sp;
            }
        }
    } else {
        // dense no-obj conf term: 48 planes × 6400 floats, float4 grid-stride
        const int nb = blk - OBJ_BLOCKS;
        const int stride = NOOBJ_BLOCKS * BLOCKSZ;
        const int nvec = BATCH * NANCH * (PLANE / 4);          // 76800
        for (int i = nb * BLOCKSZ + tid; i < nvec; i += stride) {
            int ba = i / (PLANE / 4);
            int s4 = i % (PLANE / 4);
            int b = ba / NANCH, a = ba % NANCH;
            const float4* p4 = (const float4*)(pred + ((size_t)b * CHTOT + (size_t)a * CHPA + 4) * PLANE);
            float4 v = p4[s4];
            local += (double)(softplusf(sigmoidf_(v.x)) + softplusf(sigmoidf_(v.y))
                            + softplusf(sigmoidf_(v.z)) + softplusf(sigmoidf_(v.w)));
        }
        local *= w_noobj;
    }

    // block reduction (128 threads = 2 waves) → partial slot
    for (int o = 32; o > 0; o >>= 1) local += __shfl_down(local, o, 64);
    if ((tid & 63) == 0) s_red[tid >> 6] = local;
    __syncthreads();

    if (tid == 0) {
        partial[blk] = s_red[0] + s_red[1];
        __threadfence();                                   // release partial
        unsigned int old = atomicAdd(cnt, 1u);             // device-scope ticket
        s_last = (old == TOTAL_BLOCKS - 1) ? 1 : 0;
    }
    __syncthreads();

    if (s_last) {
        __threadfence();                                   // acquire all partials
        double v = 0.0;
        for (int i = tid; i < TOTAL_BLOCKS; i += BLOCKSZ) v += partial[i];
        for (int o = 32; o > 0; o >>= 1) v += __shfl_down(v, o, 64);
        if ((tid & 63) == 0) s_red[tid >> 6] = v;
        __syncthreads();
        if (tid == 0) out[0] = (float)(s_red[0] + s_red[1]);
    }
}

extern "C" void kernel_launch(void* const* d_in, const int* in_sizes, int n_in,
                              void* d_out, int out_size, void* d_ws, size_t ws_size,
                              hipStream_t stream) {
    const float* pred    = (const float*)d_in[0];
    const float* targets = (const float*)d_in[1];
    float* out = (float*)d_out;
    double* partial = (double*)d_ws;                        // 896 doubles = 7168 B
    unsigned int* cnt = (unsigned int*)((char*)d_ws + TOTAL_BLOCKS * sizeof(double));

    hipMemsetAsync(cnt, 0, sizeof(unsigned int), stream);   // 4-byte node (poison-safe ticket)
    kmain<<<TOTAL_BLOCKS, BLOCKSZ, 0, stream>>>(pred, targets, partial, cnt, out);
}

// Round 16
// 143.848 us; speedup vs baseline: 1.1733x; 1.1733x over previous
//
#include <hip/hip_runtime.h>

// Problem constants (from reference)
#define BATCH   16
#define NTGT    50
#define NCLS    80
#define GRIDN   80                  // H = W
#define NANCH   3
#define PLANE   (GRIDN*GRIDN)       // 6400
#define CHPA    (5+NCLS)            // 85
#define CHTOT   (NANCH*CHPA)        // 255

#define OBJ_BLOCKS   (BATCH*NTGT)   // 800 — one block per (batch, target)
#define NOOBJ_BLOCKS 96             // grid-stride float4 over 48 conf planes
#define TOTAL_BLOCKS (OBJ_BLOCKS + NOOBJ_BLOCKS)  // 896
#define BLOCKSZ      128

// scaled anchors = ANCHORS / (640/80) = ANCHORS / 8
__device__ __constant__ float c_aw[3] = {14.5f, 19.5f, 46.625f};
__device__ __constant__ float c_ah[3] = {11.25f, 24.75f, 40.75f};

__device__ __forceinline__ float softplusf(float x) {
    return fmaxf(x, 0.0f) + log1pf(expf(-fabsf(x)));
}
__device__ __forceinline__ float sigmoidf_(float x) {
    return 1.0f / (1.0f + expf(-x));
}

// ---------------------------------------------------------------------------
// Measured-best structure (round 4: 142.3 µs total, fills ~127 µs of it):
//   kmain, blocks [0, 800):   obj path — block (b,t) recomputes per-batch
//     target keys (16 KB, L2-hot), dedups; if target t owns its cell, 85
//     lanes gather the cell's channels in ONE parallel round.
//   kmain, blocks [800, 896): noobj path — dense softplus(sigmoid(conf)) sum,
//     contiguous float4 loads (1.2 MB).
//   kfinal: 1 block sums the 896 partials.
// Every block WRITES partial[blockIdx] (ws is poisoned 0xAA) — no memset, no
// device fences, no atomics (round-11's fence+ticket variant cost +26 µs).
// ---------------------------------------------------------------------------
__global__ void kmain(const float* __restrict__ pred,
                      const float* __restrict__ targets,
                      double* __restrict__ partial) {
    const int blk = blockIdx.x;
    const int tid = threadIdx.x;

    const double w_coord = 5.0 / (double)BATCH;
    const double w_one   = 1.0 / (double)BATCH;
    const double w_noobj = 0.5 / (double)BATCH;

    __shared__ int   s_key[NTGT];
    __shared__ int   s_valid[NTGT];
    __shared__ int   s_cls[NTGT];
    __shared__ float s_g[4];          // gx,gy,gw,gh of THIS block's target
    __shared__ double s_red[2];

    double local = 0.0;

    if (blk < OBJ_BLOCKS) {
        const int b = blk / NTGT;
        const int t = blk % NTGT;

        if (tid < NTGT) {
            const float* t5 = targets + ((size_t)b * NTGT + tid) * 5;
            float c = t5[0], x = t5[1], y = t5[2], w = t5[3], h = t5[4];
            float ssum = c + x + y + w + h;
            float gx = x * (float)GRIDN, gy = y * (float)GRIDN;
            float gw = w * (float)GRIDN, gh = h * (float)GRIDN;
            int gi = (int)gx, gj = (int)gy;          // trunc == floor (positive)
            int valid = (ssum != 0.0f) && (gi < GRIDN) && (gj < GRIDN);
            float best = -1.0f; int bestn = 0;
            #pragma unroll
            for (int a = 0; a < NANCH; a++) {
                float inter = fminf(gw, c_aw[a]) * fminf(gh, c_ah[a]);
                float iou   = inter / (gw * gh + c_aw[a] * c_ah[a] - inter + 1e-6f);
                if (iou > best) { best = iou; bestn = a; }   // first-max wins, matches argmax
            }
            s_key[tid]   = bestn * PLANE + gj * GRIDN + gi;
            s_valid[tid] = valid;
            s_cls[tid]   = (int)c;
            if (tid == t) { s_g[0] = gx; s_g[1] = gy; s_g[2] = gw; s_g[3] = gh; }
        }
        __syncthreads();

        // last-write-wins ownership (uniform across block)
        const int mykey = s_key[t];
        bool win = (s_valid[t] != 0);
        if (win) {
            for (int t2 = t + 1; t2 < NTGT; t2++)
                if (s_valid[t2] && s_key[t2] == mykey) { win = false; break; }
        }
        if (!win) { if (tid == 0) partial[blk] = 0.0; return; }

        // tcls = UNION of class ids of all colliding valid targets
        unsigned long long mlo = 0ull; unsigned int mhi = 0u;
        for (int t2 = 0; t2 < NTGT; t2++) {
            if (s_valid[t2] && s_key[t2] == mykey) {
                int c = s_cls[t2];
                if (c < 64) mlo |= 1ull << c; else mhi |= 1u << (c - 64);
            }
        }

        const int a   = mykey / PLANE;
        const int rem = mykey % PLANE;               // gj*80 + gi
        const size_t base = ((size_t)b * CHTOT + (size_t)a * CHPA) * PLANE + rem;

        if (tid < NCLS) {
            // BCE(z,t) = softplus(z) - t*z
            float z = pred[base + (size_t)(5 + tid) * PLANE];
            bool inset = (tid < 64) ? ((mlo >> tid) & 1ull)
                                    : ((mhi >> (tid - 64)) & 1u);
            local = w_one * ((double)softplusf(z) - (inset ? (double)z : 0.0));
        } else if (tid == NCLS) {                    // x (BCE on sigmoid output)
            float sx = sigmoidf_(pred[base]);
            float tx = s_g[0] - (float)(rem % GRIDN);
            local = w_coord * ((double)softplusf(sx) - (double)tx * (double)sx);
        } else if (tid == NCLS + 1) {                // y
            float sy = sigmoidf_(pred[base + (size_t)PLANE]);
            float ty = s_g[1] - (float)(rem / GRIDN);
            local = w_coord * ((double)softplusf(sy) - (double)ty * (double)sy);
        } else if (tid == NCLS + 2) {                // w (squared error, raw)
            float pw = pred[base + 2 * (size_t)PLANE];
            float tw = logf(s_g[2] / c_aw[a] + 1e-16f);
            float d = pw - tw;
            local = w_coord * (double)d * (double)d;
        } else if (tid == NCLS + 3) {                // h
            float ph = pred[base + 3 * (size_t)PLANE];
            float th = logf(s_g[3] / c_ah[a] + 1e-16f);
            float d = ph - th;
            local = w_coord * (double)d * (double)d;
        } else if (tid == NCLS + 4) {                // conf at obj cell
            float conf = sigmoidf_(pred[base + 4 * (size_t)PLANE]);
            float sp = softplusf(conf);
            // BCE(conf,1)=softplus(conf)-conf ; also remove cell from dense noobj sum
            local = w_one * ((double)sp - (double)conf) - w_noobj * (double)sp;
        }
    } else {
        // dense no-obj conf term: 48 planes × 6400 floats, float4 grid-stride
        const int nb = blk - OBJ_BLOCKS;
        const int stride = NOOBJ_BLOCKS * BLOCKSZ;
        const int nvec = BATCH * NANCH * (PLANE / 4);          // 76800
        for (int i = nb * BLOCKSZ + tid; i < nvec; i += stride) {
            int ba = i / (PLANE / 4);
            int s4 = i % (PLANE / 4);
            int b = ba / NANCH, a = ba % NANCH;
            const float4* p4 = (const float4*)(pred + ((size_t)b * CHTOT + (size_t)a * CHPA + 4) * PLANE);
            float4 v = p4[s4];
            local += (double)(softplusf(sigmoidf_(v.x)) + softplusf(sigmoidf_(v.y))
                            + softplusf(sigmoidf_(v.z)) + softplusf(sigmoidf_(v.w)));
        }
        local *= w_noobj;
    }

    // block reduction (128 threads = 2 waves), write partial slot
    for (int o = 32; o > 0; o >>= 1) local += __shfl_down(local, o, 64);
    if ((tid & 63) == 0) s_red[tid >> 6] = local;
    __syncthreads();
    if (tid == 0) partial[blk] = s_red[0] + s_red[1];
}

__global__ void kfinal(const double* __restrict__ partial, float* __restrict__ out) {
    double v = 0.0;
    for (int i = threadIdx.x; i < TOTAL_BLOCKS; i += 256) v += partial[i];
    for (int o = 32; o > 0; o >>= 1) v += __shfl_down(v, o, 64);
    __shared__ double s[4];
    if ((threadIdx.x & 63) == 0) s[threadIdx.x >> 6] = v;
    __syncthreads();
    if (threadIdx.x == 0) out[0] = (float)(s[0] + s[1] + s[2] + s[3]);
}

extern "C" void kernel_launch(void* const* d_in, const int* in_sizes, int n_in,
                              void* d_out, int out_size, void* d_ws, size_t ws_size,
                              hipStream_t stream) {
    const float* pred    = (const float*)d_in[0];
    const float* targets = (const float*)d_in[1];
    float* out = (float*)d_out;
    double* partial = (double*)d_ws;   // TOTAL_BLOCKS doubles = 7168 B

    kmain<<<TOTAL_BLOCKS, BLOCKSZ, 0, stream>>>(pred, targets, partial);
    kfinal<<<1, 256, 0, stream>>>(partial, out);
}